// Round 2
// baseline (4741.798 us; speedup 1.0000x reference)
//
#include <hip/hip_runtime.h>
#include <hip/hip_cooperative_groups.h>

namespace cg = cooperative_groups;

#define BATCH 2048
#define HID   512
#define TSTEP 64

typedef __attribute__((ext_vector_type(8))) short bf16x8;
typedef __attribute__((ext_vector_type(4))) float f32x4;

__device__ inline unsigned short f2bf(float f) {
  unsigned int u = __builtin_bit_cast(unsigned int, f);
  unsigned int r = (u + 0x7fffu + ((u >> 16) & 1u)) >> 16;
  return (unsigned short)r;
}
__device__ inline float bf2f(unsigned short u) {
  unsigned int x = ((unsigned int)u) << 16;
  return __builtin_bit_cast(float, x);
}
__device__ inline float sigm(float x) { return 1.0f / (1.0f + __expf(-x)); }
__device__ inline float tanh_f(float x) { return 1.0f - 2.0f / (__expf(2.0f * x) + 1.0f); }

// ---------------- persistent cooperative kernel ----------------
// LDS layout (bytes): sW [128][520] bf16 = 133120 | hbuf [128][72] bf16 = 18432
//                     hOb [128][34] bf16 = 8704   | wo [8][33] f32 = 1056
#define SW_OFF 0
#define HB_OFF 133120
#define HO_OFF 151552
#define WO_OFF 160256
#define SMEM_SZ 161312

struct P {
  const float *z, *wih, *whh, *bih, *bhh, *wout, *bout;
  float* out;
  unsigned short *h0, *h1;
};

__global__ __launch_bounds__(512, 2) void k_lstm(P p) {
  extern __shared__ char smem[];
  unsigned short* sW  = (unsigned short*)(smem + SW_OFF);
  unsigned short* hbf = (unsigned short*)(smem + HB_OFF);
  unsigned short* hOb = (unsigned short*)(smem + HO_OFF);
  float* wo           = (float*)(smem + WO_OFF);

  const int bid = blockIdx.x;
  const int nt = bid & 15, bt = bid >> 4;
  const int tid = threadIdx.x;
  const int lane = tid & 63;
  const int wv = tid >> 6;
  const int mq = wv >> 1;         // 32-row group
  const int nh = wv & 1;          // 16-col half
  const int b0 = bt * 128;
  const int j0 = nt * 32;
  const int cl = lane & 15, q = lane >> 4;
  const int col = nh * 16 + cl;   // 0..31 within WG's hidden slice

  // ---- init: wo ----
  if (tid < 256) { int a = tid >> 5, j = tid & 31; wo[a * 33 + j] = p.wout[(size_t)a * HID + j0 + j]; }

  // ---- init: W_hh slice f32 -> bf16 LDS (4 strips of 32 rows x 512) ----
  for (int g4 = 0; g4 < 4; ++g4) {
    const float* gb = p.whh + ((size_t)g4 * HID + nt * 32) * HID;
#pragma unroll
    for (int v = 0; v < 4; ++v) {
      int flat = tid * 32 + v * 8;
      int rn = flat >> 9, k = flat & 511;
      float4 f0 = *(const float4*)(gb + flat);
      float4 f1 = *(const float4*)(gb + flat + 4);
      unsigned short u[8] = {f2bf(f0.x), f2bf(f0.y), f2bf(f0.z), f2bf(f0.w),
                             f2bf(f1.x), f2bf(f1.y), f2bf(f1.z), f2bf(f1.w)};
      *(bf16x8*)&sW[(size_t)(g4 * 32 + rn) * 520 + k] = *(bf16x8*)u;
    }
  }

  // ---- init: x_proj fragments in registers (exact f32) ----
  f32x4 xp[4][2];
  {
    const float* wr[4];
    float bias[4];
#pragma unroll
    for (int g4 = 0; g4 < 4; ++g4) {
      int n = g4 * HID + j0 + col;
      bias[g4] = p.bih[n] + p.bhh[n];
      wr[g4] = p.wih + (size_t)n * 72 + 8;
#pragma unroll
      for (int fm = 0; fm < 2; ++fm) { f32x4 v = {bias[g4], bias[g4], bias[g4], bias[g4]}; xp[g4][fm] = v; }
    }
    for (int k = 0; k < 64; ++k) {
      float w0 = wr[0][k], w1 = wr[1][k], w2 = wr[2][k], w3 = wr[3][k];
#pragma unroll
      for (int fm = 0; fm < 2; ++fm) {
        int br = b0 + mq * 32 + fm * 16 + q * 4;
        float z0 = p.z[(size_t)(br + 0) * 64 + k];
        float z1 = p.z[(size_t)(br + 1) * 64 + k];
        float z2 = p.z[(size_t)(br + 2) * 64 + k];
        float z3 = p.z[(size_t)(br + 3) * 64 + k];
        xp[0][fm][0] += z0 * w0; xp[0][fm][1] += z1 * w0; xp[0][fm][2] += z2 * w0; xp[0][fm][3] += z3 * w0;
        xp[1][fm][0] += z0 * w1; xp[1][fm][1] += z1 * w1; xp[1][fm][2] += z2 * w1; xp[1][fm][3] += z3 * w1;
        xp[2][fm][0] += z0 * w2; xp[2][fm][1] += z1 * w2; xp[2][fm][2] += z2 * w2; xp[2][fm][3] += z3 * w2;
        xp[3][fm][0] += z0 * w3; xp[3][fm][1] += z1 * w3; xp[3][fm][2] += z2 * w3; xp[3][fm][3] += z3 * w3;
      }
    }
  }

  // ---- init: out = b_out ----
  for (int i = bid * 512 + tid; i < BATCH * TSTEP * 8; i += 256 * 512)
    p.out[i] = p.bout[i & 7];

  f32x4 cc[2]; cc[0] = (f32x4){0,0,0,0}; cc[1] = (f32x4){0,0,0,0};

  cg::grid_group grid = cg::this_grid();
  __threadfence();
  grid.sync();   // out initialized, W staged

  // staging assignment: thread covers row sr, 16 bf16 at sc*16
  const int sr = tid >> 2, sc = tid & 3;
  const int lds_w = sr * 72 + sc * 16;    // in shorts (byte = sr*144 + sc*32)

  for (int t = 0; t < TSTEP; ++t) {
    f32x4 acc[4][2];
#pragma unroll
    for (int g4 = 0; g4 < 4; ++g4)
#pragma unroll
      for (int fm = 0; fm < 2; ++fm) acc[g4][fm] = xp[g4][fm];

    if (t > 0) {
      const unsigned short* hsrc = ((t & 1) ? p.h0 : p.h1) + (size_t)b0 * HID;
      const size_t go = (size_t)sr * HID + sc * 16;
      int4 ra = *(const int4*)(hsrc + go);
      int4 rb = *(const int4*)(hsrc + go + 8);
      for (int kk = 0; kk < 8; ++kk) {
        __syncthreads();                       // prior reads of hbf done
        *(int4*)&hbf[lds_w]     = ra;
        *(int4*)&hbf[lds_w + 8] = rb;
        __syncthreads();
        if (kk < 7) {
          size_t kb = go + (size_t)(kk + 1) * 64;
          ra = *(const int4*)(hsrc + kb);
          rb = *(const int4*)(hsrc + kb + 8);
        }
#pragma unroll
        for (int ks = 0; ks < 2; ++ks) {
          bf16x8 af[2], bfr[4];
#pragma unroll
          for (int fm = 0; fm < 2; ++fm)
            af[fm] = *(const bf16x8*)&hbf[(size_t)(mq * 32 + fm * 16 + cl) * 72 + ks * 32 + q * 8];
#pragma unroll
          for (int g4 = 0; g4 < 4; ++g4)
            bfr[g4] = *(const bf16x8*)&sW[(size_t)(g4 * 32 + nh * 16 + cl) * 520 + kk * 64 + ks * 32 + q * 8];
#pragma unroll
          for (int g4 = 0; g4 < 4; ++g4)
#pragma unroll
            for (int fm = 0; fm < 2; ++fm)
              acc[g4][fm] = __builtin_amdgcn_mfma_f32_16x16x32_bf16(af[fm], bfr[g4], acc[g4][fm], 0, 0, 0);
        }
      }
    }

    // ---- cell (c in registers), write h to global ping-pong + LDS hO ----
    unsigned short* hcur = (t & 1) ? p.h1 : p.h0;
#pragma unroll
    for (int fm = 0; fm < 2; ++fm) {
      int brow = b0 + mq * 32 + fm * 16 + q * 4;
#pragma unroll
      for (int r = 0; r < 4; ++r) {
        float iv = sigm(acc[0][fm][r]);
        float fv = sigm(acc[1][fm][r]);
        float gv = tanh_f(acc[2][fm][r]);
        float ov = sigm(acc[3][fm][r]);
        float cn = fv * cc[fm][r] + iv * gv;
        cc[fm][r] = cn;
        float hv = ov * tanh_f(cn);
        unsigned short hb = f2bf(hv);
        hcur[(size_t)(brow + r) * HID + j0 + col] = hb;
        hOb[(size_t)(mq * 32 + fm * 16 + q * 4 + r) * 34 + col] = hb;
      }
    }
    __syncthreads();   // hO ready

    // ---- partial output projection (32-j slice) -> atomicAdd ----
#pragma unroll
    for (int pp = 0; pp < 2; ++pp) {
      int idx = tid * 2 + pp;
      int row = idx >> 3, a = idx & 7;
      float s = 0.0f;
#pragma unroll
      for (int j = 0; j < 32; ++j) s += bf2f(hOb[(size_t)row * 34 + j]) * wo[a * 33 + j];
      atomicAdd(&p.out[((size_t)(b0 + row) * TSTEP + t) * 8 + a], s);
    }

    __threadfence();
    grid.sync();       // h_t + out_t published
  }
}

// ---------------- fallback path (round-1, multi-launch) ----------------
__global__ void k_warr(const float* __restrict__ whh, unsigned short* __restrict__ warr) {
  int g = blockIdx.x * 256 + threadIdx.x;
  int k = g & 511;
  int rl = g >> 9;
  int r = rl & 31, gt = (rl >> 5) & 3, nt = rl >> 7;
  int src_row = gt * HID + nt * 32 + r;
  warr[g] = f2bf(whh[(size_t)src_row * HID + k]);
}

__global__ void k_xproj(const float* __restrict__ z, const float* __restrict__ wih,
                        const float* __restrict__ bih, const float* __restrict__ bhh,
                        float* __restrict__ xp) {
  __shared__ float zt[16][64];
  int n = blockIdx.x * 256 + threadIdx.x;
  int b0 = blockIdx.y * 16;
  for (int i = threadIdx.x; i < 16 * 64; i += 256)
    zt[i >> 6][i & 63] = z[(size_t)(b0 + (i >> 6)) * 64 + (i & 63)];
  __syncthreads();
  float bias = bih[n] + bhh[n];
  float acc[16];
#pragma unroll
  for (int b = 0; b < 16; ++b) acc[b] = bias;
  const float* wr = wih + (size_t)n * 72 + 8;
  for (int k = 0; k < 64; ++k) {
    float w = wr[k];
#pragma unroll
    for (int b = 0; b < 16; ++b) acc[b] += zt[b][k] * w;
  }
#pragma unroll
  for (int b = 0; b < 16; ++b) xp[(size_t)(b0 + b) * 2048 + n] = acc[b];
}

__global__ void k_initout(const float* __restrict__ bout, float* __restrict__ out) {
  int g = blockIdx.x * 256 + threadIdx.x;
  out[g] = bout[g & 7];
}

__global__ __launch_bounds__(512) void k_stepA(
    const unsigned short* __restrict__ hprev, unsigned short* __restrict__ hcur,
    const float* __restrict__ xp, float* __restrict__ cst,
    const unsigned short* __restrict__ warr, const float* __restrict__ wout,
    float* __restrict__ proj_dst, int t) {
  const int nt = blockIdx.x, bt = blockIdx.y;
  const int tid = threadIdx.x;
  const int lane = tid & 63;
  const int wv = tid >> 6;
  const int mq = wv >> 1;
  const int nh = wv & 1;
  const int b0 = bt * 128;
  const int j0 = nt * 32;
  const int cl = lane & 15, q = lane >> 4;

  __shared__ unsigned short hA[128 * 72];
  __shared__ unsigned short wB[128 * 72];
  __shared__ float hO[128][33];
  __shared__ float wo[8][33];

  if (tid < 256) { int a = tid >> 5, j = tid & 31; wo[a][j] = wout[(size_t)a * HID + j0 + j]; }

  f32x4 acc[4][2];
#pragma unroll
  for (int g4 = 0; g4 < 4; ++g4)
#pragma unroll
    for (int fm = 0; fm < 2; ++fm) {
      int brow = b0 + mq * 32 + fm * 16 + q * 4;
      const float* p = xp + (size_t)brow * 2048 + g4 * HID + j0 + nh * 16 + cl;
      f32x4 v; v[0] = p[0]; v[1] = p[2048]; v[2] = p[4096]; v[3] = p[6144];
      acc[g4][fm] = v;
    }

  if (t > 0) {
    const unsigned short* hsrc = hprev + (size_t)b0 * HID;
    const unsigned short* wsrc = warr + (size_t)nt * 128 * HID;
    const int sr = tid >> 3, sc = tid & 7;
    const size_t go1 = (size_t)sr * HID + sc * 8;
    const size_t go2 = (size_t)(sr + 64) * HID + sc * 8;
    const int lo1 = sr * 72 + sc * 8, lo2 = (sr + 64) * 72 + sc * 8;
    int4 ra = *(const int4*)(hsrc + go1);
    int4 rb = *(const int4*)(hsrc + go2);
    int4 rc = *(const int4*)(wsrc + go1);
    int4 rd = *(const int4*)(wsrc + go2);
    for (int kk = 0; kk < 8; ++kk) {
      __syncthreads();
      *(int4*)&hA[lo1] = ra; *(int4*)&hA[lo2] = rb;
      *(int4*)&wB[lo1] = rc; *(int4*)&wB[lo2] = rd;
      __syncthreads();
      if (kk < 7) {
        size_t kb = (size_t)(kk + 1) * 64;
        ra = *(const int4*)(hsrc + go1 + kb);
        rb = *(const int4*)(hsrc + go2 + kb);
        rc = *(const int4*)(wsrc + go1 + kb);
        rd = *(const int4*)(wsrc + go2 + kb);
      }
#pragma unroll
      for (int ks = 0; ks < 2; ++ks) {
        bf16x8 af[2], bfr[4];
#pragma unroll
        for (int fm = 0; fm < 2; ++fm)
          af[fm] = *(const bf16x8*)&hA[(mq * 32 + fm * 16 + cl) * 72 + ks * 32 + q * 8];
#pragma unroll
        for (int g4 = 0; g4 < 4; ++g4)
          bfr[g4] = *(const bf16x8*)&wB[(g4 * 32 + nh * 16 + cl) * 72 + ks * 32 + q * 8];
#pragma unroll
        for (int g4 = 0; g4 < 4; ++g4)
#pragma unroll
          for (int fm = 0; fm < 2; ++fm)
            acc[g4][fm] = __builtin_amdgcn_mfma_f32_16x16x32_bf16(af[fm], bfr[g4], acc[g4][fm], 0, 0, 0);
      }
    }
  }

#pragma unroll
  for (int fm = 0; fm < 2; ++fm) {
    int brow = b0 + mq * 32 + fm * 16 + q * 4;
    int colx = j0 + nh * 16 + cl;
#pragma unroll
    for (int r = 0; r < 4; ++r) {
      float iv = sigm(acc[0][fm][r]);
      float fv = sigm(acc[1][fm][r]);
      float gv = tanh_f(acc[2][fm][r]);
      float ov = sigm(acc[3][fm][r]);
      size_t cix = (size_t)(brow + r) * HID + colx;
      float cp = (t > 0) ? cst[cix] : 0.0f;
      float cn = fv * cp + iv * gv;
      cst[cix] = cn;
      float hv = ov * tanh_f(cn);
      hcur[cix] = f2bf(hv);
      hO[mq * 32 + fm * 16 + q * 4 + r][nh * 16 + cl] = hv;
    }
  }
  __syncthreads();

#pragma unroll
  for (int pq = 0; pq < 2; ++pq) {
    int idx = tid * 2 + pq;
    int row = idx >> 3, a = idx & 7;
    float s = 0.0f;
#pragma unroll
    for (int j = 0; j < 32; ++j) s += hO[row][j] * wo[a][j];
    atomicAdd(&proj_dst[((size_t)(b0 + row) * TSTEP + t) * 8 + a], s);
  }
}

extern "C" void kernel_launch(void* const* d_in, const int* in_sizes, int n_in,
                              void* d_out, int out_size, void* d_ws, size_t ws_size,
                              hipStream_t stream) {
  const float* z    = (const float*)d_in[0];
  const float* wih  = (const float*)d_in[1];
  const float* whh  = (const float*)d_in[2];
  const float* bih  = (const float*)d_in[3];
  const float* bhh  = (const float*)d_in[4];
  const float* wout = (const float*)d_in[5];
  const float* bout = (const float*)d_in[6];
  float* out = (float*)d_out;

  char* ws = (char*)d_ws;
  unsigned short* h0 = (unsigned short*)(ws);              // 2 MB
  unsigned short* h1 = (unsigned short*)(ws + (2u << 20)); // 2 MB

  P pp;
  pp.z = z; pp.wih = wih; pp.whh = whh; pp.bih = bih; pp.bhh = bhh;
  pp.wout = wout; pp.bout = bout; pp.out = out; pp.h0 = h0; pp.h1 = h1;

  static_assert(SMEM_SZ <= 163840, "LDS budget");
  hipFuncSetAttribute((const void*)k_lstm, hipFuncAttributeMaxDynamicSharedMemorySize, SMEM_SZ);
  void* args[] = {&pp};
  hipError_t e = hipLaunchCooperativeKernel((const void*)k_lstm, dim3(256), dim3(512),
                                            args, SMEM_SZ, stream);
  if (e == hipSuccess) return;

  // ---- fallback: round-1 multi-launch path ----
  float* xp            = (float*)(ws + (4u << 20));          // 16 MB
  float* cst           = (float*)(ws + (20u << 20));         // 4 MB
  unsigned short* f0   = (unsigned short*)(ws + (24u << 20));// 2 MB
  unsigned short* f1   = (unsigned short*)(ws + (26u << 20));// 2 MB
  unsigned short* warr = (unsigned short*)(ws + (28u << 20));// 2 MB

  k_warr<<<dim3(4096), dim3(256), 0, stream>>>(whh, warr);
  k_xproj<<<dim3(8, 128), dim3(256), 0, stream>>>(z, wih, bih, bhh, xp);
  k_initout<<<dim3(4096), dim3(256), 0, stream>>>(bout, out);
  for (int t = 0; t < TSTEP; ++t) {
    const unsigned short* hp = (t & 1) ? f0 : f1;
    unsigned short* hc = (t & 1) ? f1 : f0;
    k_stepA<<<dim3(16, 16), dim3(512), 0, stream>>>(hp, hc, xp, cst, warr, wout, out, t);
  }
}

// Round 3
// 1413.855 us; speedup vs baseline: 3.3538x; 3.3538x over previous
//
#include <hip/hip_runtime.h>

// LSTM decoder B=2048, Z=64, A=8, H=512, T=64.
// gates = [h | z] @ [W_hh | W_ih_z]^T + bias  (K folded: 512 + 64 = 576)
// bf16 MFMA 16x16x32; A (h,z) direct from global; B (W_cat) via global_load_lds
// double-buffered with XOR-swizzled source (bank-conflict-free ds_read_b128).

#define HID   512
#define TSTEP 64
#define KCAT  576

typedef __attribute__((ext_vector_type(8))) short bf16x8;
typedef __attribute__((ext_vector_type(4))) float f32x4;

__device__ inline unsigned short f2bf(float f) {
  unsigned int u = __builtin_bit_cast(unsigned int, f);
  unsigned int r = (u + 0x7fffu + ((u >> 16) & 1u)) >> 16;
  return (unsigned short)r;
}
__device__ inline float bf2f(unsigned short u) {
  unsigned int x = ((unsigned int)u) << 16;
  return __builtin_bit_cast(float, x);
}
__device__ inline float sigm(float x) { return 1.0f / (1.0f + __expf(-x)); }
__device__ inline float tanh_f(float x) { return 1.0f - 2.0f / (__expf(2.0f * x) + 1.0f); }

__device__ inline void gl16(const unsigned short* g, unsigned short* l) {
  __builtin_amdgcn_global_load_lds(
      (const __attribute__((address_space(1))) unsigned int*)g,
      (__attribute__((address_space(3))) unsigned int*)l, 16, 0, 0);
}

// ---- prep: W_cat[n][0..575] = [W_hh[n][:] | W_ih[n][8..71]] bf16 ----
__global__ void k_prep_w(const float* __restrict__ whh, const float* __restrict__ wih,
                         unsigned short* __restrict__ wcat) {
  int c = blockIdx.x * 256 + threadIdx.x;      // 2048*72 chunks of 8
  if (c >= 2048 * 72) return;
  int n = c / 72, kc = (c % 72) * 8;
  unsigned short u[8];
#pragma unroll
  for (int e = 0; e < 8; ++e) {
    int k = kc + e;
    float v = (k < 512) ? whh[(size_t)n * 512 + k] : wih[(size_t)n * 72 + 8 + (k - 512)];
    u[e] = f2bf(v);
  }
  *(bf16x8*)&wcat[(size_t)n * KCAT + kc] = *(bf16x8*)u;
}

__global__ void k_prep_zb(const float* __restrict__ z, const float* __restrict__ bih,
                          const float* __restrict__ bhh, unsigned short* __restrict__ zbf,
                          float* __restrict__ bias) {
  int c = blockIdx.x * 256 + threadIdx.x;
  if (c < 16384) {                              // z: 2048x64 -> bf16
    int row = c >> 3, kc = (c & 7) * 8;
    unsigned short u[8];
#pragma unroll
    for (int e = 0; e < 8; ++e) u[e] = f2bf(z[(size_t)row * 64 + kc + e]);
    *(bf16x8*)&zbf[(size_t)row * 64 + kc] = *(bf16x8*)u;
  } else if (c < 16384 + 2048) {
    int n = c - 16384;
    bias[n] = bih[n] + bhh[n];
  }
}

__global__ void k_initout(const float* __restrict__ bout, float* __restrict__ out) {
  int g = blockIdx.x * 256 + threadIdx.x;
  out[g] = bout[g & 7];
}

// ---- one step. grid (nt 16, bt 16), 512 thr. WG: 128 batch x 32 hid x 4 gates ----
template <int USE_PART>
__global__ __launch_bounds__(512, 2) void k_step(
    const unsigned short* __restrict__ hprev, unsigned short* __restrict__ hnext,
    const unsigned short* __restrict__ wcat, const unsigned short* __restrict__ zbf,
    const float* __restrict__ bias, float* __restrict__ cst,
    const float* __restrict__ wout, float* __restrict__ dst, int t) {
  __shared__ unsigned short Bb[2][128 * 64];    // B chunk dbuf, 16 KB each
  __shared__ unsigned short hO[128 * 34];
  __shared__ float wo[8 * 33];

  const int nt = blockIdx.x, bt = blockIdx.y;
  const int tid = threadIdx.x;
  const int lane = tid & 63;
  const int wv = tid >> 6;
  const int mq = wv >> 1, nh = wv & 1;
  const int cl = lane & 15, q8 = lane >> 4;
  const int b0 = bt * 128;
  const int j0 = nt * 32;

  if (tid < 256) { int a = tid >> 5, j = tid & 31; wo[a * 33 + j] = wout[(size_t)a * HID + j0 + j]; }

  // staging addresses (XOR-swizzled source, linear LDS dest)
  const int r1 = tid >> 3, qq = tid & 7;
  const int n1 = (r1 >> 5) * HID + j0 + (r1 & 31);
  const int n2 = ((r1 + 64) >> 5) * HID + j0 + ((r1 + 64) & 31);
  const unsigned short* wsrc1 = wcat + (size_t)n1 * KCAT + (qq ^ (r1 & 7)) * 8;
  const unsigned short* wsrc2 = wcat + (size_t)n2 * KCAT + (qq ^ (r1 & 7)) * 8;

  // acc init = bias (per-lane col is fixed per gate)
  const int col = j0 + nh * 16 + cl;
  f32x4 acc[4][2];
#pragma unroll
  for (int g4 = 0; g4 < 4; ++g4) {
    float bv = bias[g4 * HID + col];
    f32x4 v = {bv, bv, bv, bv};
    acc[g4][0] = v; acc[g4][1] = v;
  }

  // c prefetch (thread-private contiguous layout)
  const size_t cbase = (((size_t)bt * 16 + nt) * 512 + tid) * 8;
  f32x4 cold0 = {0, 0, 0, 0}, cold1 = {0, 0, 0, 0};
  if (t > 0) { cold0 = *(const f32x4*)&cst[cbase]; cold1 = *(const f32x4*)&cst[cbase + 4]; }

  const int arow0 = b0 + mq * 32 + cl;
  const int arow1 = arow0 + 16;

  const int kk0 = (t > 0) ? 0 : 8;              // t=0: h==0, only z-chunk
  // prologue stage
  {
    unsigned short* lb = &Bb[0][wv * 512];
    gl16(wsrc1 + kk0 * 64, lb);
    gl16(wsrc2 + kk0 * 64, lb + 4096);
  }
  __syncthreads();

  for (int kk = kk0; kk <= 8; ++kk) {
    const int bu = (kk - kk0) & 1;
    if (kk < 8) {
      unsigned short* lb = &Bb[bu ^ 1][wv * 512];
      gl16(wsrc1 + (kk + 1) * 64, lb);
      gl16(wsrc2 + (kk + 1) * 64, lb + 4096);
    }
    const unsigned short* Bl = &Bb[bu][0];
#pragma unroll
    for (int ks = 0; ks < 2; ++ks) {
      bf16x8 a0, a1;
      if (kk < 8) {
        a0 = *(const bf16x8*)(hprev + (size_t)arow0 * HID + kk * 64 + ks * 32 + q8 * 8);
        a1 = *(const bf16x8*)(hprev + (size_t)arow1 * HID + kk * 64 + ks * 32 + q8 * 8);
      } else {
        a0 = *(const bf16x8*)(zbf + (size_t)arow0 * 64 + ks * 32 + q8 * 8);
        a1 = *(const bf16x8*)(zbf + (size_t)arow1 * 64 + ks * 32 + q8 * 8);
      }
#pragma unroll
      for (int g4 = 0; g4 < 4; ++g4) {
        int rl = g4 * 32 + nh * 16 + cl;
        int mp = (ks * 4 + q8) ^ (cl & 7);      // rl&7 == cl&7
        bf16x8 bf = *(const bf16x8*)&Bl[rl * 64 + mp * 8];
        acc[g4][0] = __builtin_amdgcn_mfma_f32_16x16x32_bf16(a0, bf, acc[g4][0], 0, 0, 0);
        acc[g4][1] = __builtin_amdgcn_mfma_f32_16x16x32_bf16(a1, bf, acc[g4][1], 0, 0, 0);
      }
    }
    __syncthreads();
  }

  // ---- cell (c private), h -> LDS ----
  f32x4 cn0, cn1;
#pragma unroll
  for (int mt = 0; mt < 2; ++mt) {
    f32x4 cold = mt ? cold1 : cold0;
    f32x4 cnew;
#pragma unroll
    for (int r = 0; r < 4; ++r) {
      float iv = sigm(acc[0][mt][r]);
      float fv = sigm(acc[1][mt][r]);
      float gv = tanh_f(acc[2][mt][r]);
      float ov = sigm(acc[3][mt][r]);
      float cc = fv * cold[r] + iv * gv;
      cnew[r] = cc;
      float hv = ov * tanh_f(cc);
      hO[(mq * 32 + mt * 16 + q8 * 4 + r) * 34 + nh * 16 + cl] = f2bf(hv);
    }
    if (mt) cn1 = cnew; else cn0 = cnew;
  }
  *(f32x4*)&cst[cbase] = cn0;
  *(f32x4*)&cst[cbase + 4] = cn1;
  __syncthreads();

  // ---- h -> global (coalesced 16B) ----
  {
    int row = tid >> 2, sg = tid & 3;
    unsigned short tmp[8];
#pragma unroll
    for (int e = 0; e < 8; ++e) tmp[e] = hO[row * 34 + sg * 8 + e];
    *(int4*)&hnext[(size_t)(b0 + row) * HID + j0 + sg * 8] = *(int4*)tmp;
  }

  // ---- partial output projection ----
#pragma unroll
  for (int pq = 0; pq < 2; ++pq) {
    int idx = tid * 2 + pq, row = idx >> 3, a = idx & 7;
    float s = 0.0f;
#pragma unroll
    for (int j = 0; j < 32; ++j) s += bf2f(hO[row * 34 + j]) * wo[a * 33 + j];
    if (USE_PART)
      dst[(size_t)nt * 1048576 + (size_t)(b0 + row) * 512 + t * 8 + a] = s;
    else
      atomicAdd(&dst[(size_t)(b0 + row) * 512 + t * 8 + a], s);
  }
}

__global__ void k_final(const float* __restrict__ part, const float* __restrict__ bout,
                        float* __restrict__ out) {
  int g = blockIdx.x * 256 + threadIdx.x;       // (b*64+t)*8+a
  float s = bout[g & 7];
#pragma unroll
  for (int n = 0; n < 16; ++n) s += part[(size_t)n * 1048576 + g];
  out[g] = s;
}

extern "C" void kernel_launch(void* const* d_in, const int* in_sizes, int n_in,
                              void* d_out, int out_size, void* d_ws, size_t ws_size,
                              hipStream_t stream) {
  const float* z    = (const float*)d_in[0];
  const float* wih  = (const float*)d_in[1];
  const float* whh  = (const float*)d_in[2];
  const float* bih  = (const float*)d_in[3];
  const float* bhh  = (const float*)d_in[4];
  const float* wout = (const float*)d_in[5];
  const float* bout = (const float*)d_in[6];
  float* out = (float*)d_out;

  char* ws = (char*)d_ws;
  unsigned short* wcat = (unsigned short*)(ws);                    // 2,359,296
  unsigned short* zbf  = (unsigned short*)(ws + 2359296);          //   262,144
  float* bias          = (float*)(ws + 2621440);                   //     8,192
  float* cst           = (float*)(ws + 2629632);                   // 4,194,304
  unsigned short* h0   = (unsigned short*)(ws + 6823936);          // 2,097,152
  unsigned short* h1   = (unsigned short*)(ws + 8921088);          // 2,097,152
  float* part          = (float*)(ws + 11018240);                  // 67,108,864
  const bool use_part = ws_size >= 11018240ull + 67108864ull;

  k_prep_w<<<dim3(576), dim3(256), 0, stream>>>(whh, wih, wcat);
  k_prep_zb<<<dim3(72), dim3(256), 0, stream>>>(z, bih, bhh, zbf, bias);
  if (!use_part) k_initout<<<dim3(4096), dim3(256), 0, stream>>>(bout, out);

  for (int t = 0; t < TSTEP; ++t) {
    const unsigned short* hp = (t & 1) ? h0 : h1;
    unsigned short* hn = (t & 1) ? h1 : h0;
    if (use_part)
      k_step<1><<<dim3(16, 16), dim3(512), 0, stream>>>(hp, hn, wcat, zbf, bias, cst, wout, part, t);
    else
      k_step<0><<<dim3(16, 16), dim3(512), 0, stream>>>(hp, hn, wcat, zbf, bias, cst, wout, out, t);
  }
  if (use_part) k_final<<<dim3(4096), dim3(256), 0, stream>>>(part, bout, out);
}